// Round 6
// baseline (6451.779 us; speedup 1.0000x reference)
//
#include <hip/hip_runtime.h>

// LSTM_26877905338550 — B=1048576 independent tiny-MLP LSTM chains, T=3.
// R6: weights via UNIFORM SCALAR LOADS (s_load -> SGPR, v_fmac v,s,v),
// no LDS at all. R3-R5 were LDS-BW-bound: ~2500 ds_read_b128 per elem*t
// (~30k cyc/wave*t of LDS pipe) vs ~20k cyc of FMA -> 65% VALUBusy cap.
// Scalar path uses the separate SMEM/K$ pipe (weights are wave-uniform,
// compile-time offsets), freeing VALU+LDS entirely. No LDS -> 24 waves/CU.

#define NB 1048576

// packed weight offsets (floats), all 16B aligned
#define OWX   0      // Wx   [30][8]
#define OWH   240    // Wh   [30][32] (30 used)
#define OHTB  1200   // ht_b [32]
#define OW0   1232   // W0'  [30][32]
#define OB0   2192   // b0   [32]
#define OW1   2224   // W1   [45][32]
#define OB1   3664   // b1   [48]
#define OW2   3712   // W2   [40][48] (45 used)
#define OB2   5632   // b2   [40]
#define OW3   5672   // W3   [30][40]
#define OB3   6872   // b3   [32]
#define OGW   6904   // gW   [120][32] (30 used)
#define OGB   10744  // gb   [120]
#define OPW   10864  // pW   [32]  (p2@p1 fused)
#define OPB   10896  // pb   scalar
#define WTOT  10912  // padded to float4 multiple

__global__ void prep_kernel(const float* __restrict__ htW, const float* __restrict__ htb,
                            const float* __restrict__ w0,  const float* __restrict__ b0,
                            const float* __restrict__ w1,  const float* __restrict__ b1,
                            const float* __restrict__ w2,  const float* __restrict__ b2,
                            const float* __restrict__ w3,  const float* __restrict__ b3,
                            const float* __restrict__ gw,  const float* __restrict__ gb,
                            const float* __restrict__ p1w, const float* __restrict__ p1b,
                            const float* __restrict__ p2w, const float* __restrict__ p2b,
                            float* __restrict__ ws) {
  int tid = threadIdx.x;
  for (int i = tid; i < 240; i += 256) {            // Wx [30][8]
    int j = i >> 3, k = i & 7;
    ws[OWX + i] = htW[j * 38 + k];
  }
  for (int i = tid; i < 960; i += 256) {            // Wh [30][32]
    int j = i >> 5, k = i & 31;
    ws[OWH + i] = (k < 30) ? htW[j * 38 + 8 + k] : 0.f;
  }
  for (int i = tid; i < 32; i += 256) ws[OHTB + i] = (i < 30) ? htb[i] : 0.f;
  for (int i = tid; i < 960; i += 256) {            // W0' = W0[:, :30] + W0[:, 30:]
    int j = i >> 5, k = i & 31;
    ws[OW0 + i] = (k < 30) ? (w0[j * 60 + k] + w0[j * 60 + 30 + k]) : 0.f;
  }
  for (int i = tid; i < 32; i += 256) ws[OB0 + i] = (i < 30) ? b0[i] : 0.f;
  for (int i = tid; i < 1440; i += 256) {           // W1 [45][32]
    int j = i >> 5, k = i & 31;
    ws[OW1 + i] = (k < 30) ? w1[j * 30 + k] : 0.f;
  }
  for (int i = tid; i < 48; i += 256) ws[OB1 + i] = (i < 45) ? b1[i] : 0.f;
  for (int i = tid; i < 1920; i += 256) {           // W2 [40][48]
    int j = i / 48, k = i % 48;
    ws[OW2 + i] = (k < 45) ? w2[j * 45 + k] : 0.f;
  }
  for (int i = tid; i < 40; i += 256) ws[OB2 + i] = b2[i];
  for (int i = tid; i < 1200; i += 256) {           // W3 [30][40]
    int j = i / 40, k = i % 40;
    ws[OW3 + i] = w3[j * 40 + k];
  }
  for (int i = tid; i < 32; i += 256) ws[OB3 + i] = (i < 30) ? b3[i] : 0.f;
  for (int i = tid; i < 3840; i += 256) {           // gW [120][32]
    int j = i >> 5, k = i & 31;
    ws[OGW + i] = (k < 30) ? gw[j * 30 + k] : 0.f;
  }
  for (int i = tid; i < 120; i += 256) ws[OGB + i] = gb[i];
  for (int i = tid; i < 32; i += 256) {             // pW = p2W @ p1W
    float acc = 0.f;
    if (i < 30)
      for (int m = 0; m < 10; m++) acc += p2w[m] * p1w[m * 30 + i];
    ws[OPW + i] = acc;
  }
  for (int i = tid; i < WTOT - 10897; i += 256) ws[10897 + i] = 0.f;  // pad
  if (tid == 0) {
    float acc = p2b[0];
    for (int m = 0; m < 10; m++) acc += p2w[m] * p1b[m];
    ws[OPB] = acc;
  }
}

__device__ __forceinline__ float ftanh(float v) {
  float u = __builtin_amdgcn_exp2f(v * 2.8853900817779268f);
  return 1.0f - 2.0f * __builtin_amdgcn_rcpf(u + 1.0f);
}
__device__ __forceinline__ float fsigm(float v) {
  float u = __builtin_amdgcn_exp2f(v * -1.4426950408889634f);
  return __builtin_amdgcn_rcpf(1.0f + u);
}

#define SBAR() __builtin_amdgcn_sched_barrier(0)

// out[j] = (TANH? tanh : id)(sum_k W[woff + j*STRIDE + k] * in[k] + W[boff + j])
// W reads are wave-uniform, compile-time offsets -> s_load (scalar pipe).
template <int OUT, int IN, int STRIDE, bool TANH>
__device__ __forceinline__ void layer(const float* __restrict__ Wl, int woff, int boff,
                                      const float* in, float* outv) {
  constexpr int K4 = IN / 4;
#pragma unroll
  for (int j = 0; j < OUT; j++) {
    float acc = Wl[boff + j];
#pragma unroll
    for (int k4 = 0; k4 < K4; k4++) {
      float4 wv = *(const float4*)&Wl[woff + j * STRIDE + k4 * 4];
      acc = fmaf(wv.x, in[k4 * 4 + 0], acc);
      acc = fmaf(wv.y, in[k4 * 4 + 1], acc);
      acc = fmaf(wv.z, in[k4 * 4 + 2], acc);
      acc = fmaf(wv.w, in[k4 * 4 + 3], acc);
    }
    if constexpr ((IN & 3) >= 2) {
      float2 wv = *(const float2*)&Wl[woff + j * STRIDE + K4 * 4];
      acc = fmaf(wv.x, in[K4 * 4 + 0], acc);
      acc = fmaf(wv.y, in[K4 * 4 + 1], acc);
      if constexpr ((IN & 3) == 3)
        acc = fmaf(Wl[woff + j * STRIDE + K4 * 4 + 2], in[K4 * 4 + 2], acc);
    } else if constexpr ((IN & 3) == 1) {
      acc = fmaf(Wl[woff + j * STRIDE + K4 * 4], in[K4 * 4], acc);
    }
    outv[j] = TANH ? ftanh(acc) : acc;
    if ((j & 3) == 3) SBAR();   // bound SGPR prefetch window (~4 rows)
  }
}

__global__ void __launch_bounds__(256)
lstm_main(const float* __restrict__ x, const float* __restrict__ w,
          float* __restrict__ out) {
  int tid = threadIdx.x;
  int b = blockIdx.x * 256 + tid;
  const float* xb = x + (size_t)b * 24;

  float hidden[30], cell[30];
#pragma unroll
  for (int j = 0; j < 30; j++) { hidden[j] = 0.f; cell[j] = 0.f; }

  for (int t = 0; t < 3; t++) {  // NOT unrolled: keep code small (I$)
    float4 xa = *(const float4*)(xb + t * 8);
    float4 xc = *(const float4*)(xb + t * 8 + 4);

    // hs = Wx@x_t + Wh@hidden + ht_b  (t=0: skip Wh, hidden==0)
    float hs[30];
#pragma unroll
    for (int j = 0; j < 30; j++) {
      float acc = w[OHTB + j];
      float4 wa = *(const float4*)&w[OWX + j * 8];
      float4 wc = *(const float4*)&w[OWX + j * 8 + 4];
      acc = fmaf(wa.x, xa.x, acc);
      acc = fmaf(wa.y, xa.y, acc);
      acc = fmaf(wa.z, xa.z, acc);
      acc = fmaf(wa.w, xa.w, acc);
      acc = fmaf(wc.x, xc.x, acc);
      acc = fmaf(wc.y, xc.y, acc);
      acc = fmaf(wc.z, xc.z, acc);
      acc = fmaf(wc.w, xc.w, acc);
      if (t > 0) {
#pragma unroll
        for (int k4 = 0; k4 < 7; k4++) {
          float4 wv = *(const float4*)&w[OWH + j * 32 + k4 * 4];
          acc = fmaf(wv.x, hidden[k4 * 4 + 0], acc);
          acc = fmaf(wv.y, hidden[k4 * 4 + 1], acc);
          acc = fmaf(wv.z, hidden[k4 * 4 + 2], acc);
          acc = fmaf(wv.w, hidden[k4 * 4 + 3], acc);
        }
        float2 wv = *(const float2*)&w[OWH + j * 32 + 28];
        acc = fmaf(wv.x, hidden[28], acc);
        acc = fmaf(wv.y, hidden[29], acc);
      }
      hs[j] = acc;
      if ((j & 3) == 3) SBAR();
    }
    SBAR();
    float a0[30];
    layer<30, 30, 32, true>(w, OW0, OB0, hs, a0);
    SBAR();
    float a1[45];
    layer<45, 30, 32, true>(w, OW1, OB1, a0, a1);
    SBAR();
    float a2[40];
    layer<40, 45, 48, true>(w, OW2, OB2, a1, a2);
    SBAR();
    float a3[30];
    layer<30, 40, 40, true>(w, OW3, OB3, a2, a3);
    SBAR();
    // gates + LSTM update
#pragma unroll
    for (int j = 0; j < 30; j++) {
      float d0 = w[OGB + j];
      float d1 = w[OGB + 30 + j];
      float d2 = w[OGB + 60 + j];
      float d3 = w[OGB + 90 + j];
#pragma unroll
      for (int k4 = 0; k4 < 7; k4++) {
        float4 wi = *(const float4*)&w[OGW + (j)*32 + k4 * 4];
        float4 wf = *(const float4*)&w[OGW + (30 + j) * 32 + k4 * 4];
        float4 wo = *(const float4*)&w[OGW + (60 + j) * 32 + k4 * 4];
        float4 wg = *(const float4*)&w[OGW + (90 + j) * 32 + k4 * 4];
#pragma unroll
        for (int q = 0; q < 4; q++) {
          float a = a3[k4 * 4 + q];
          d0 = fmaf(q == 0 ? wi.x : q == 1 ? wi.y : q == 2 ? wi.z : wi.w, a, d0);
          d1 = fmaf(q == 0 ? wf.x : q == 1 ? wf.y : q == 2 ? wf.z : wf.w, a, d1);
          d2 = fmaf(q == 0 ? wo.x : q == 1 ? wo.y : q == 2 ? wo.z : wo.w, a, d2);
          d3 = fmaf(q == 0 ? wg.x : q == 1 ? wg.y : q == 2 ? wg.z : wg.w, a, d3);
        }
      }
      {
        float2 wi = *(const float2*)&w[OGW + (j)*32 + 28];
        float2 wf = *(const float2*)&w[OGW + (30 + j) * 32 + 28];
        float2 wo = *(const float2*)&w[OGW + (60 + j) * 32 + 28];
        float2 wg = *(const float2*)&w[OGW + (90 + j) * 32 + 28];
        d0 = fmaf(wi.x, a3[28], d0); d0 = fmaf(wi.y, a3[29], d0);
        d1 = fmaf(wf.x, a3[28], d1); d1 = fmaf(wf.y, a3[29], d1);
        d2 = fmaf(wo.x, a3[28], d2); d2 = fmaf(wo.y, a3[29], d2);
        d3 = fmaf(wg.x, a3[28], d3); d3 = fmaf(wg.y, a3[29], d3);
      }
      float ig = fsigm(ftanh(d0));
      float fg = fsigm(ftanh(d1));
      float og = fsigm(ftanh(d2));
      float gg = ftanh(ftanh(d3));
      float c = fmaf(fg, cell[j], ig * gg);  // t=0: cell==0, exact
      cell[j] = c;
      hidden[j] = og * ftanh(c);
      SBAR();   // per-j: 4 rows x 32 floats already saturate SGPR window
    }
    SBAR();
  }
  // out = pW @ hidden + pb
  float acc = w[OPB];
#pragma unroll
  for (int k = 0; k < 30; k++) acc = fmaf(w[OPW + k], hidden[k], acc);
  out[b] = acc;
}

extern "C" void kernel_launch(void* const* d_in, const int* in_sizes, int n_in,
                              void* d_out, int out_size, void* d_ws, size_t ws_size,
                              hipStream_t stream) {
  const float* x   = (const float*)d_in[0];
  const float* htW = (const float*)d_in[1];
  const float* htb = (const float*)d_in[2];
  const float* w0  = (const float*)d_in[3];
  const float* b0  = (const float*)d_in[4];
  const float* w1  = (const float*)d_in[5];
  const float* b1  = (const float*)d_in[6];
  const float* w2  = (const float*)d_in[7];
  const float* b2  = (const float*)d_in[8];
  const float* w3  = (const float*)d_in[9];
  const float* b3  = (const float*)d_in[10];
  const float* gw  = (const float*)d_in[11];
  const float* gb  = (const float*)d_in[12];
  const float* p1w = (const float*)d_in[13];
  const float* p1b = (const float*)d_in[14];
  const float* p2w = (const float*)d_in[15];
  const float* p2b = (const float*)d_in[16];
  float* ws = (float*)d_ws;
  float* out = (float*)d_out;

  hipLaunchKernelGGL(prep_kernel, dim3(1), dim3(256), 0, stream,
                     htW, htb, w0, b0, w1, b1, w2, b2, w3, b3, gw, gb,
                     p1w, p1b, p2w, p2b, ws);
  hipLaunchKernelGGL(lstm_main, dim3(NB / 256), dim3(256), 0, stream, x, ws, out);
}

// Round 7
// 630.843 us; speedup vs baseline: 10.2272x; 10.2272x over previous
//
#include <hip/hip_runtime.h>

// LSTM_26877905338550 — B=1048576 tiny-MLP LSTM chains, T=3. R7: MFMA.
// Each wave = 16 batch elements (one M-tile). Every layer is a
// mfma_f32_16x16x32_bf16 GEMM tile; weights pre-swizzled into B-fragment
// order in LDS (prep kernel), activations bounce via wave-private
// XOR-swizzled LDS buffer [16 elems][64 k] bf16. Gates consumed in
// C-layout registers; cell state = 8 VGPR f32; head = shfl_xor reduce.
// Layouts: A: m=lane&15, k=(lane>>4)*8+i (m162); B: n=lane&15,
// k=(lane>>4)*8+i; C/D: col(n)=lane&15, row(m)=(lane>>4)*4+reg (m89).

#define NB 1048576

typedef unsigned short ushortT;
typedef __attribute__((ext_vector_type(8))) short short8;
typedef __attribute__((ext_vector_type(4))) float f32x4;

#define MFMA __builtin_amdgcn_mfma_f32_16x16x32_bf16

// bias region offsets (floats, within bias block)
#define BHS 0
#define BB0 32
#define BB1 64
#define BB2 112
#define BB3 160
#define BGB 192
#define BPW 320
#define BPB 352
#define NBIAS 356           // padded to float4 multiple
#define NWF 13824           // 27 tiles * 512 u16

__device__ __forceinline__ ushortT bf16r(float v) {
  unsigned u = __builtin_bit_cast(unsigned, v);
  u += 0x7fff + ((u >> 16) & 1);      // RNE
  return (ushortT)(u >> 16);
}

__global__ void prep_kernel(const float* __restrict__ htW, const float* __restrict__ htb,
                            const float* __restrict__ w0,  const float* __restrict__ b0,
                            const float* __restrict__ w1,  const float* __restrict__ b1,
                            const float* __restrict__ w2,  const float* __restrict__ b2,
                            const float* __restrict__ w3,  const float* __restrict__ b3,
                            const float* __restrict__ gw,  const float* __restrict__ gb,
                            const float* __restrict__ p1w, const float* __restrict__ p1b,
                            const float* __restrict__ p2w, const float* __restrict__ p2b,
                            float* __restrict__ ws) {
  int tid = threadIdx.x;
  ushortT* wf = (ushortT*)ws;
  float* bias = ws + NWF / 2;   // 13824 u16 = 6912 floats
  // tile tables: matrix select, k0, n0 for the 27 MFMA tiles
  const int msel[27] = {0,0,0,0, 1,1, 2,2,2, 3,3,3,3,3,3, 4,4,4,4, 5,5,5,5,5,5,5,5};
  const int tk0[27]  = {0,32,0,32, 0,0, 0,0,0, 0,32,0,32,0,32, 0,32,0,32, 0,0,0,0,0,0,0,0};
  const int tn0[27]  = {0,0,16,16, 0,16, 0,16,32, 0,0,16,16,32,32, 0,0,16,16,
                        0,16,32,48,64,80,96,112};
  for (int i = tid; i < NWF; i += 256) {
    int tau = i >> 9, s = i & 511, l = s >> 3, ii = s & 7;
    int n = tn0[tau] + (l & 15);
    int k = tk0[tau] + ((l >> 4) << 3) + ii;
    float v = 0.f;
    switch (msel[tau]) {
      case 0: if (n < 30 && k < 38) v = htW[n * 38 + k]; break;                 // [x(8);h(30)]
      case 1: if (n < 30 && k < 30) v = w0[n * 60 + k] + w0[n * 60 + 30 + k]; break;
      case 2: if (n < 45 && k < 30) v = w1[n * 30 + k]; break;
      case 3: if (n < 40 && k < 45) v = w2[n * 45 + k]; break;
      case 4: if (n < 30 && k < 40) v = w3[n * 40 + k]; break;
      default: { int g = n >> 5, j = n & 31;
                 if (j < 30 && k < 30) v = gw[(g * 30 + j) * 30 + k]; } break;
    }
    wf[i] = bf16r(v);
  }
  for (int i = tid; i < NBIAS; i += 256) {
    float v = 0.f;
    if (i < 32)       { if (i < 30) v = htb[i]; }
    else if (i < 64)  { int j = i - 32;  if (j < 30) v = b0[j]; }
    else if (i < 112) { int j = i - 64;  if (j < 45) v = b1[j]; }
    else if (i < 160) { int j = i - 112; if (j < 40) v = b2[j]; }
    else if (i < 192) { int j = i - 160; if (j < 30) v = b3[j]; }
    else if (i < 320) { int j = i - 192; int g = j >> 5, q = j & 31;
                        if (q < 30) v = gb[g * 30 + q]; }
    else if (i < 352) { int j = i - 320;
                        if (j < 30) { float a = 0.f;
                          for (int m = 0; m < 10; m++) a += p2w[m] * p1w[m * 30 + j];
                          v = a; } }
    else if (i == 352){ float a = p2b[0];
                        for (int m = 0; m < 10; m++) a += p2w[m] * p1b[m];
                        v = a; }
    bias[i] = v;
  }
}

__device__ __forceinline__ float ftanh(float v) {
  float u = __builtin_amdgcn_exp2f(v * 2.8853900817779268f);
  return 1.0f - 2.0f * __builtin_amdgcn_rcpf(u + 1.0f);
}
__device__ __forceinline__ float fsigm(float v) {
  float u = __builtin_amdgcn_exp2f(v * -1.4426950408889634f);
  return __builtin_amdgcn_rcpf(1.0f + u);
}

__global__ void __launch_bounds__(256) lstm_main(const float* __restrict__ x,
                                                 const float* __restrict__ ws,
                                                 float* __restrict__ out) {
  __shared__ __align__(16) ushortT wfL[NWF];
  __shared__ __align__(16) float biasL[NBIAS];
  __shared__ __align__(16) ushortT ABall[4][1024];   // per-wave [16 e][64 k] bf16
  int tid = threadIdx.x;
  {
    const float4* src = (const float4*)ws;
    for (int i = tid; i < NWF / 8; i += 256) ((float4*)wfL)[i] = src[i];          // 1728
    for (int i = tid; i < NBIAS / 4; i += 256) ((float4*)biasL)[i] = src[NWF / 8 + i];
  }
  __syncthreads();

  int lane = tid & 63, wv = tid >> 6;
  ushortT* ab = ABall[wv];
  int eb = blockIdx.x * 64 + wv * 16;

  // zero the wave's act buffer (swizzle-consistent)
  {
    int e = lane >> 2;
#pragma unroll
    for (int q = 0; q < 8; q++) {
      int byte = lane * 32 + q * 4;
      byte ^= (e & 7) << 4;
      *(unsigned*)((char*)ab + byte) = 0u;
    }
  }

  auto ldA = [&](int kf) -> short8 {
    int byte = ((lane & 15) << 7) + (kf << 6) + ((lane >> 4) << 4);
    byte ^= (lane & 7) << 4;                     // e = lane&15
    return *(const short8*)((const char*)ab + byte);
  };
  auto ldB = [&](int tau) -> short8 {
    return *(const short8*)(wfL + tau * 512 + lane * 8);
  };
  auto bias4 = [&](int boff, int n0) -> f32x4 {
    float bv = biasL[boff + n0 + (lane & 15)];
    return (f32x4){bv, bv, bv, bv};
  };
  auto stTile = [&](f32x4 c, int n0) {           // tanh -> bf16 -> act buffer
    int n = n0 + (lane & 15);
#pragma unroll
    for (int r = 0; r < 4; r++) {
      int e = ((lane >> 4) << 2) + r;
      float v = ftanh(c[r]);
      int byte = (e << 7) + (n << 1);
      byte ^= (e & 7) << 4;
      *(ushortT*)((char*)ab + byte) = bf16r(v);
    }
  };

  float cell0[4] = {0.f, 0.f, 0.f, 0.f};
  float cell1[4] = {0.f, 0.f, 0.f, 0.f};

#pragma unroll
  for (int t = 0; t < 3; t++) {
    // stage x(t) into k[0..7] of the act buffer
    {
      int e = lane >> 2, f = (lane & 3) * 2;
      float2 xv = *(const float2*)(x + (size_t)(eb + e) * 24 + t * 8 + f);
      unsigned pk = (unsigned)bf16r(xv.x) | ((unsigned)bf16r(xv.y) << 16);
      int byte = (e << 7) + (f << 1);
      byte ^= (e & 7) << 4;
      *(unsigned*)((char*)ab + byte) = pk;
    }
    short8 af0, af1, b;
    f32x4 c0, c1, c2;
    // L1: hs = WxWh @ [x;hidden] + ht_b     K=64, N=32
    af0 = ldA(0); af1 = ldA(1);
    b = ldB(0);  c0 = bias4(BHS, 0);  c0 = MFMA(af0, b, c0, 0, 0, 0);
    b = ldB(1);  c0 = MFMA(af1, b, c0, 0, 0, 0);
    b = ldB(2);  c1 = bias4(BHS, 16); c1 = MFMA(af0, b, c1, 0, 0, 0);
    b = ldB(3);  c1 = MFMA(af1, b, c1, 0, 0, 0);
    stTile(c0, 0); stTile(c1, 16);
    // L2: a0 = tanh(W0' @ hs + b0)          K=32, N=32
    af0 = ldA(0);
    b = ldB(4);  c0 = bias4(BB0, 0);  c0 = MFMA(af0, b, c0, 0, 0, 0);
    b = ldB(5);  c1 = bias4(BB0, 16); c1 = MFMA(af0, b, c1, 0, 0, 0);
    stTile(c0, 0); stTile(c1, 16);
    // L3: a1                                 K=32, N=48
    af0 = ldA(0);
    b = ldB(6);  c0 = bias4(BB1, 0);  c0 = MFMA(af0, b, c0, 0, 0, 0);
    b = ldB(7);  c1 = bias4(BB1, 16); c1 = MFMA(af0, b, c1, 0, 0, 0);
    b = ldB(8);  c2 = bias4(BB1, 32); c2 = MFMA(af0, b, c2, 0, 0, 0);
    stTile(c0, 0); stTile(c1, 16); stTile(c2, 32);
    // L4: a2                                 K=64, N=48
    af0 = ldA(0); af1 = ldA(1);
    b = ldB(9);  c0 = bias4(BB2, 0);  c0 = MFMA(af0, b, c0, 0, 0, 0);
    b = ldB(10); c0 = MFMA(af1, b, c0, 0, 0, 0);
    b = ldB(11); c1 = bias4(BB2, 16); c1 = MFMA(af0, b, c1, 0, 0, 0);
    b = ldB(12); c1 = MFMA(af1, b, c1, 0, 0, 0);
    b = ldB(13); c2 = bias4(BB2, 32); c2 = MFMA(af0, b, c2, 0, 0, 0);
    b = ldB(14); c2 = MFMA(af1, b, c2, 0, 0, 0);
    stTile(c0, 0); stTile(c1, 16); stTile(c2, 32);
    // L5: a3                                 K=64, N=32
    af0 = ldA(0); af1 = ldA(1);
    b = ldB(15); c0 = bias4(BB3, 0);  c0 = MFMA(af0, b, c0, 0, 0, 0);
    b = ldB(16); c0 = MFMA(af1, b, c0, 0, 0, 0);
    b = ldB(17); c1 = bias4(BB3, 16); c1 = MFMA(af0, b, c1, 0, 0, 0);
    b = ldB(18); c1 = MFMA(af1, b, c1, 0, 0, 0);
    stTile(c0, 0); stTile(c1, 16);
    // L6: gates                              K=32, N=128 (4 gates x 32)
    af0 = ldA(0);
    f32x4 gi0, gi1, gf0, gf1, go0, go1, gg0, gg1;
    b = ldB(19); gi0 = bias4(BGB, 0);   gi0 = MFMA(af0, b, gi0, 0, 0, 0);
    b = ldB(20); gi1 = bias4(BGB, 16);  gi1 = MFMA(af0, b, gi1, 0, 0, 0);
    b = ldB(21); gf0 = bias4(BGB, 32);  gf0 = MFMA(af0, b, gf0, 0, 0, 0);
    b = ldB(22); gf1 = bias4(BGB, 48);  gf1 = MFMA(af0, b, gf1, 0, 0, 0);
    b = ldB(23); go0 = bias4(BGB, 64);  go0 = MFMA(af0, b, go0, 0, 0, 0);
    b = ldB(24); go1 = bias4(BGB, 80);  go1 = MFMA(af0, b, go1, 0, 0, 0);
    b = ldB(25); gg0 = bias4(BGB, 96);  gg0 = MFMA(af0, b, gg0, 0, 0, 0);
    b = ldB(26); gg1 = bias4(BGB, 112); gg1 = MFMA(af0, b, gg1, 0, 0, 0);
    // LSTM update in C-layout: lane holds (e=(lane>>4)*4+r, j=lane&15 [+16])
    float hid0[4], hid1[4];
#pragma unroll
    for (int r = 0; r < 4; r++) {
      float ig = fsigm(ftanh(gi0[r]));
      float fg = fsigm(ftanh(gf0[r]));
      float og = fsigm(ftanh(go0[r]));
      float gg = ftanh(ftanh(gg0[r]));
      float c = fmaf(fg, cell0[r], ig * gg);
      cell0[r] = c;
      hid0[r] = og * ftanh(c);
      float ig1 = fsigm(ftanh(gi1[r]));
      float fg1 = fsigm(ftanh(gf1[r]));
      float og1 = fsigm(ftanh(go1[r]));
      float gg1v = ftanh(ftanh(gg1[r]));
      float c1v = fmaf(fg1, cell1[r], ig1 * gg1v);
      cell1[r] = c1v;
      hid1[r] = og1 * ftanh(c1v);
    }
    if (t < 2) {
      // hidden -> act buffer k[8..39] (j=30,31 write exact 0 into pad 38,39)
#pragma unroll
      for (int r = 0; r < 4; r++) {
        int e = ((lane >> 4) << 2) + r;
        int b0a = (e << 7) + ((8 + (lane & 15)) << 1);
        b0a ^= (e & 7) << 4;
        *(ushortT*)((char*)ab + b0a) = bf16r(hid0[r]);
        int b1a = (e << 7) + ((24 + (lane & 15)) << 1);
        b1a ^= (e & 7) << 4;
        *(ushortT*)((char*)ab + b1a) = bf16r(hid1[r]);
      }
    } else {
      // out[e] = pb + sum_j pW[j] * hidden[e][j]
      float pw0 = biasL[BPW + (lane & 15)];
      float pw1 = biasL[BPW + 16 + (lane & 15)];
      float pb = biasL[BPB];
      float p[4];
#pragma unroll
      for (int r = 0; r < 4; r++) {
        float s = pw0 * hid0[r] + pw1 * hid1[r];
        s += __shfl_xor(s, 1);
        s += __shfl_xor(s, 2);
        s += __shfl_xor(s, 4);
        s += __shfl_xor(s, 8);
        p[r] = s;
      }
      if ((lane & 15) == 0) {
        int e0 = (lane >> 4) << 2;
#pragma unroll
        for (int r = 0; r < 4; r++) out[eb + e0 + r] = pb + p[r];
      }
    }
  }
}

extern "C" void kernel_launch(void* const* d_in, const int* in_sizes, int n_in,
                              void* d_out, int out_size, void* d_ws, size_t ws_size,
                              hipStream_t stream) {
  const float* x   = (const float*)d_in[0];
  const float* htW = (const float*)d_in[1];
  const float* htb = (const float*)d_in[2];
  const float* w0  = (const float*)d_in[3];
  const float* b0  = (const float*)d_in[4];
  const float* w1  = (const float*)d_in[5];
  const float* b1  = (const float*)d_in[6];
  const float* w2  = (const float*)d_in[7];
  const float* b2  = (const float*)d_in[8];
  const float* w3  = (const float*)d_in[9];
  const float* b3  = (const float*)d_in[10];
  const float* gw  = (const float*)d_in[11];
  const float* gb  = (const float*)d_in[12];
  const float* p1w = (const float*)d_in[13];
  const float* p1b = (const float*)d_in[14];
  const float* p2w = (const float*)d_in[15];
  const float* p2b = (const float*)d_in[16];
  float* ws = (float*)d_ws;
  float* out = (float*)d_out;

  hipLaunchKernelGGL(prep_kernel, dim3(1), dim3(256), 0, stream,
                     htW, htb, w0, b0, w1, b1, w2, b2, w3, b3, gw, gb,
                     p1w, p1b, p2w, p2b, ws);
  hipLaunchKernelGGL(lstm_main, dim3(NB / 64), dim3(256), 0, stream, x, ws, out);
}